// Round 4
// baseline (1023.083 us; speedup 1.0000x reference)
//
#include <hip/hip_runtime.h>
#include <hip/hip_bf16.h>

#define NROWS 500000
#define DIM   256
#define BSEG  16384
#define LDSP  264   // LDS pitch in bf16 elems: 256 + 8 pad

typedef __attribute__((ext_vector_type(8))) short short8;
typedef __attribute__((ext_vector_type(4))) float floatx4;

// ws layout (bytes):
//   [0,        16M)  local_rep  f32 [BSEG][DIM]
//   [16M,      32M)  global_rep f32 [BSEG][DIM]
//   [32M,      40M)  H1         bf16 [BSEG][DIM]
//   [40M,        +128K) W1t bf16 k-tiled
//   [40M+128K,  +128K) W2t bf16 k-tiled
//   [40M+256K,  +256K) W4t bf16 k-tiled (K=512)

__device__ __forceinline__ unsigned short f2bf(float f) {
  unsigned u = __float_as_uint(f);
  unsigned r = u + 0x7fffu + ((u >> 16) & 1u);  // RNE
  return (unsigned short)(r >> 16);
}
__device__ __forceinline__ float bf2f(short s) {
  return __uint_as_float(((unsigned)(unsigned short)s) << 16);
}
__device__ __forceinline__ float fast_sigmoid(float z) {
  return 1.0f / (1.0f + __expf(-z));
}

__global__ __launch_bounds__(1024) void k_zero(float* __restrict__ p, int n4) {
  int i = blockIdx.x * blockDim.x + threadIdx.x;
  if (i < n4) ((float4*)p)[i] = make_float4(0.f, 0.f, 0.f, 0.f);
}

// One launch converts W1 (kt 0-7), W2 (kt 8-15), W4 (kt 16-31).
__global__ __launch_bounds__(256) void k_convert_all(
    const float* __restrict__ W1, const float* __restrict__ W2,
    const float* __restrict__ W4, short* __restrict__ W1t,
    short* __restrict__ W2t, short* __restrict__ W4t)
{
  int blk = blockIdx.x;          // 0..31
  const float* W; short* out; int kt;
  if (blk < 8)       { W = W1; out = W1t; kt = blk; }
  else if (blk < 16) { W = W2; out = W2t; kt = blk - 8; }
  else               { W = W4; out = W4t; kt = blk - 16; }
  int n = threadIdx.x;
  short tmp[32];
#pragma unroll
  for (int kk = 0; kk < 32; ++kk)
    tmp[kk] = (short)f2bf(W[(size_t)(kt * 32 + kk) * DIM + n]);
  size_t base = ((size_t)kt * 256 + n) * 32;
#pragma unroll
  for (int kk = 0; kk < 32; kk += 4)
    *(short4*)&out[base + kk] = *(short4*)&tmp[kk];
}

// local_rep[s][c] = sum_{r in seg s} x[r][c] * mask[r]; batch sorted.
__global__ __launch_bounds__(256) void k_seg_local(
    const float* __restrict__ x, const int* __restrict__ batch,
    const float* __restrict__ mask, float* __restrict__ local_rep,
    int rows_per_block)
{
  const int col = threadIdx.x;
  int r0 = blockIdx.x * rows_per_block;
  int r1 = min(NROWS, r0 + rows_per_block);
  if (r0 >= r1) return;
  float acc = 0.f;
  int cur = batch[r0];
  int r = r0;
  for (; r + 4 <= r1; r += 4) {
    float xv0 = x[(size_t)(r + 0) * DIM + col];
    float xv1 = x[(size_t)(r + 1) * DIM + col];
    float xv2 = x[(size_t)(r + 2) * DIM + col];
    float xv3 = x[(size_t)(r + 3) * DIM + col];
    int s0 = batch[r], s1 = batch[r + 1], s2 = batch[r + 2], s3 = batch[r + 3];
    float m0 = mask[r], m1 = mask[r + 1], m2 = mask[r + 2], m3 = mask[r + 3];
    if (s0 != cur) { atomicAdd(&local_rep[(size_t)cur * DIM + col], acc); acc = 0.f; cur = s0; }
    acc = fmaf(xv0, m0, acc);
    if (s1 != cur) { atomicAdd(&local_rep[(size_t)cur * DIM + col], acc); acc = 0.f; cur = s1; }
    acc = fmaf(xv1, m1, acc);
    if (s2 != cur) { atomicAdd(&local_rep[(size_t)cur * DIM + col], acc); acc = 0.f; cur = s2; }
    acc = fmaf(xv2, m2, acc);
    if (s3 != cur) { atomicAdd(&local_rep[(size_t)cur * DIM + col], acc); acc = 0.f; cur = s3; }
    acc = fmaf(xv3, m3, acc);
  }
  for (; r < r1; ++r) {
    int s = batch[r];
    float xv = x[(size_t)r * DIM + col];
    float mv = mask[r];
    if (s != cur) { atomicAdd(&local_rep[(size_t)cur * DIM + col], acc); acc = 0.f; cur = s; }
    acc = fmaf(xv, mv, acc);
  }
  atomicAdd(&local_rep[(size_t)cur * DIM + col], acc);
}

// stage 64x256 fp32 tile -> bf16 LDS (pitch LDSP), rows clamped to maxrow
__device__ __forceinline__ void stage_tile(const float* __restrict__ A, int row0,
                                           int maxrow, short* xs, int tid)
{
#pragma unroll
  for (int it = 0; it < 16; ++it) {
    int linear = it * 256 + tid;
    int r = linear >> 6;      // 64 float4 per row
    int c4 = linear & 63;
    int row = min(row0 + r, maxrow);
    float4 v = *(const float4*)&A[(size_t)row * DIM + c4 * 4];
    short4 o;
    o.x = (short)f2bf(v.x); o.y = (short)f2bf(v.y);
    o.z = (short)f2bf(v.z); o.w = (short)f2bf(v.w);
    *(short4*)&xs[r * LDSP + c4 * 4] = o;
  }
}

// K=256 MFMA pass, double-buffered fragments across kt iterations.
__device__ __forceinline__ void mfma_pass(const short* xs, const short* __restrict__ Wt,
                                          floatx4 acc[4][4], int lane15, int quad, int n0)
{
  short8 bfr[2][4], afr[2][4];
#pragma unroll
  for (int jn = 0; jn < 4; ++jn)
    bfr[0][jn] = *(const short8*)&Wt[(size_t)(n0 + jn * 16 + lane15) * 32 + quad * 8];
#pragma unroll
  for (int i = 0; i < 4; ++i)
    afr[0][i] = *(const short8*)&xs[(i * 16 + lane15) * LDSP + quad * 8];

#pragma unroll
  for (int kt = 0; kt < 8; ++kt) {
    const int cur = kt & 1, nxt = cur ^ 1;
    if (kt < 7) {
      const int k2 = kt + 1;
#pragma unroll
      for (int jn = 0; jn < 4; ++jn)
        bfr[nxt][jn] = *(const short8*)&Wt[(size_t)k2 * 8192 + (n0 + jn * 16 + lane15) * 32 + quad * 8];
#pragma unroll
      for (int i = 0; i < 4; ++i)
        afr[nxt][i] = *(const short8*)&xs[(i * 16 + lane15) * LDSP + k2 * 32 + quad * 8];
    }
#pragma unroll
    for (int i = 0; i < 4; ++i)
#pragma unroll
      for (int jn = 0; jn < 4; ++jn)
        acc[i][jn] = __builtin_amdgcn_mfma_f32_16x16x32_bf16(afr[cur][i], bfr[cur][jn], acc[i][jn], 0, 0, 0);
  }
}

// H1 = bf16(local_rep @ W1 + b1)
__global__ __launch_bounds__(256) void k_h1_mfma(
    const float* __restrict__ A, const short* __restrict__ Wt,
    const float* __restrict__ bias, short* __restrict__ H1bf)
{
  __shared__ short xs[64 * LDSP];
  const int tid = threadIdx.x;
  const int row0 = blockIdx.x * 64;
  stage_tile(A, row0, BSEG - 1, xs, tid);
  __syncthreads();
  const int lane = tid & 63, wave = tid >> 6;
  const int lane15 = lane & 15, quad = lane >> 4;
  const int n0 = wave * 64;
  floatx4 acc[4][4];
#pragma unroll
  for (int i = 0; i < 4; ++i)
#pragma unroll
    for (int j = 0; j < 4; ++j) acc[i][j] = (floatx4)0.f;
  mfma_pass(xs, Wt, acc, lane15, quad, n0);
#pragma unroll
  for (int i = 0; i < 4; ++i)
#pragma unroll
    for (int jn = 0; jn < 4; ++jn) {
      int col = n0 + jn * 16 + lane15;
      float bv = bias[col];
#pragma unroll
      for (int r = 0; r < 4; ++r) {
        int row = row0 + i * 16 + quad * 4 + r;
        H1bf[(size_t)row * DIM + col] = (short)f2bf(acc[i][jn][r] + bv);
      }
    }
}

// Fused: z = x@W2 + b2 + H1[batch]; att = sigmoid(z)@w3; global_rep += segsum(x*att)
__global__ __launch_bounds__(256) void k_fused_main(
    const float* __restrict__ x, const int* __restrict__ batch,
    const short* __restrict__ W2t, const float* __restrict__ b2,
    const float* __restrict__ w3, const short* __restrict__ H1bf,
    float* __restrict__ global_rep)
{
  __shared__ short xs[64 * LDSP];
  __shared__ int   seg_s[64];
  __shared__ float att_s[64];
  const int tid = threadIdx.x;
  const int row0 = blockIdx.x * 64;

  stage_tile(x, row0, NROWS - 1, xs, tid);
  if (tid < 64) {
    seg_s[tid] = batch[min(row0 + tid, NROWS - 1)];
    att_s[tid] = 0.f;
  }
  __syncthreads();

  const int lane = tid & 63, wave = tid >> 6;
  const int lane15 = lane & 15, quad = lane >> 4;
  const int n0 = wave * 64;
  floatx4 acc[4][4];
#pragma unroll
  for (int i = 0; i < 4; ++i)
#pragma unroll
    for (int j = 0; j < 4; ++j) acc[i][j] = (floatx4)0.f;
  mfma_pass(xs, W2t, acc, lane15, quad, n0);

  // epilogue: z -> sigmoid -> dot w3 -> att per row
  float b2v[4], w3v[4];
#pragma unroll
  for (int jn = 0; jn < 4; ++jn) {
    int col = n0 + jn * 16 + lane15;
    b2v[jn] = b2[col];
    w3v[jn] = w3[col];
  }
  float part[4][4];
#pragma unroll
  for (int i = 0; i < 4; ++i)
#pragma unroll
    for (int r = 0; r < 4; ++r) {
      int rl = i * 16 + quad * 4 + r;
      int seg = seg_s[rl];
      float p = 0.f;
#pragma unroll
      for (int jn = 0; jn < 4; ++jn) {
        int col = n0 + jn * 16 + lane15;
        float h = bf2f(H1bf[(size_t)seg * DIM + col]);
        float z = acc[i][jn][r] + h + b2v[jn];
        p = fmaf(fast_sigmoid(z), w3v[jn], p);
      }
      part[i][r] = p;
    }
  // reduce over the 16 lanes (cols) of each quad
#pragma unroll
  for (int off = 1; off < 16; off <<= 1)
#pragma unroll
    for (int i = 0; i < 4; ++i)
#pragma unroll
      for (int r = 0; r < 4; ++r)
        part[i][r] += __shfl_xor(part[i][r], off, 64);
  if (lane15 == 0) {
#pragma unroll
    for (int i = 0; i < 4; ++i)
#pragma unroll
      for (int r = 0; r < 4; ++r)
        atomicAdd(&att_s[i * 16 + quad * 4 + r], part[i][r]);
  }
  __syncthreads();

  // phase 2: weighted segsum of x*att from LDS (bf16 x)
  const int col = tid;
  const int rmax = min(64, NROWS - row0);
  float acc2 = 0.f;
  int cur = seg_s[0];
  for (int r = 0; r < rmax; ++r) {
    int s = seg_s[r];
    float xv = bf2f(xs[r * LDSP + col]);
    float av = att_s[r];
    if (s != cur) {
      atomicAdd(&global_rep[(size_t)cur * DIM + col], acc2);
      acc2 = 0.f; cur = s;
    }
    acc2 = fmaf(xv, av, acc2);
  }
  atomicAdd(&global_rep[(size_t)cur * DIM + col], acc2);
}

// out = local_rep @ W4[0:256] + global_rep @ W4[256:512] + b4
__global__ __launch_bounds__(256) void k_out_mfma(
    const float* __restrict__ local_rep, const float* __restrict__ global_rep,
    const short* __restrict__ W4t, const float* __restrict__ b4,
    float* __restrict__ out)
{
  __shared__ short xs[64 * LDSP];
  const int tid = threadIdx.x;
  const int row0 = blockIdx.x * 64;
  const int lane = tid & 63, wave = tid >> 6;
  const int lane15 = lane & 15, quad = lane >> 4;
  const int n0 = wave * 64;
  floatx4 acc[4][4];
#pragma unroll
  for (int i = 0; i < 4; ++i)
#pragma unroll
    for (int j = 0; j < 4; ++j) acc[i][j] = (floatx4)0.f;

  stage_tile(local_rep, row0, BSEG - 1, xs, tid);
  __syncthreads();
  mfma_pass(xs, W4t, acc, lane15, quad, n0);
  __syncthreads();
  stage_tile(global_rep, row0, BSEG - 1, xs, tid);
  __syncthreads();
  mfma_pass(xs, W4t + (size_t)8 * 8192, acc, lane15, quad, n0);

#pragma unroll
  for (int i = 0; i < 4; ++i)
#pragma unroll
    for (int jn = 0; jn < 4; ++jn) {
      int col = n0 + jn * 16 + lane15;
      float bv = b4[col];
#pragma unroll
      for (int r = 0; r < 4; ++r) {
        int row = row0 + i * 16 + quad * 4 + r;
        out[(size_t)row * DIM + col] = acc[i][jn][r] + bv;
      }
    }
}

extern "C" void kernel_launch(void* const* d_in, const int* in_sizes, int n_in,
                              void* d_out, int out_size, void* d_ws, size_t ws_size,
                              hipStream_t stream) {
  (void)in_sizes; (void)n_in; (void)out_size; (void)ws_size;
  const float* x    = (const float*)d_in[0];
  const int*   batch= (const int*)d_in[1];
  const float* mask = (const float*)d_in[2];
  const float* W1 = (const float*)d_in[4];
  const float* b1 = (const float*)d_in[5];
  const float* W2 = (const float*)d_in[6];
  const float* b2 = (const float*)d_in[7];
  const float* w3 = (const float*)d_in[8];
  const float* W4 = (const float*)d_in[9];
  const float* b4 = (const float*)d_in[10];
  float* out = (float*)d_out;

  char* base = (char*)d_ws;
  float* local_rep  = (float*)(base);
  float* global_rep = (float*)(base + (size_t)16 * 1024 * 1024);
  short* H1bf       = (short*)(base + (size_t)32 * 1024 * 1024);
  short* W1t        = (short*)(base + (size_t)40 * 1024 * 1024);
  short* W2t        = (short*)(base + (size_t)40 * 1024 * 1024 + 128 * 1024);
  short* W4t        = (short*)(base + (size_t)40 * 1024 * 1024 + 256 * 1024);

  // zero local_rep + global_rep
  int n4 = 2 * BSEG * DIM / 4;
  hipLaunchKernelGGL(k_zero, dim3(n4 / 1024), dim3(1024), 0, stream, local_rep, n4);

  // all weight conversions in one launch
  hipLaunchKernelGGL(k_convert_all, dim3(32), dim3(256), 0, stream,
                     W1, W2, W4, W1t, W2t, W4t);

  const int SEG_BLOCKS = 4096;
  int rpb = (NROWS + SEG_BLOCKS - 1) / SEG_BLOCKS;
  hipLaunchKernelGGL(k_seg_local, dim3(SEG_BLOCKS), dim3(256), 0, stream,
                     x, batch, mask, local_rep, rpb);

  hipLaunchKernelGGL(k_h1_mfma, dim3(BSEG / 64), dim3(256), 0, stream,
                     local_rep, W1t, b1, H1bf);

  hipLaunchKernelGGL(k_fused_main, dim3((NROWS + 63) / 64), dim3(256), 0, stream,
                     x, batch, W2t, b2, w3, H1bf, global_rep);

  hipLaunchKernelGGL(k_out_mfma, dim3(BSEG / 64), dim3(256), 0, stream,
                     local_rep, global_rep, W4t, b4, out);
}

// Round 5
// 985.269 us; speedup vs baseline: 1.0384x; 1.0384x over previous
//
#include <hip/hip_runtime.h>
#include <hip/hip_bf16.h>

#define NROWS 500000
#define DIM   256
#define BSEG  16384
#define LDSP  264              // LDS pitch in bf16 elems: 256 + 8 pad
#define NTILE 7813             // ceil(NROWS/64)
#define TILE_B (64 * LDSP * 2) // 33792 bytes per x tile image

typedef __attribute__((ext_vector_type(8))) short short8;
typedef __attribute__((ext_vector_type(4))) float floatx4;

// async global->LDS, 16B per lane (wave-uniform LDS base + lane*16)
#define GLD16(gsrc, ldst)                                                      \
  __builtin_amdgcn_global_load_lds(                                            \
      (const __attribute__((address_space(1))) unsigned int*)(gsrc),           \
      (__attribute__((address_space(3))) unsigned int*)(ldst), 16, 0, 0)

// ws layout (bytes):
//   [0,   16M)  local_rep  f32 [BSEG][DIM]
//   [16M, 32M)  global_rep f32 [BSEG][DIM]
//   [32M, 40M)  H1 bf16 [BSEG][DIM]
//   [40M, +128K) W1t  | +128K W2t | +256K W4t   (bf16 k-tiled)
//   [48M, +264M) xbf16 padded tile images [NTILE][64*264]

__device__ __forceinline__ unsigned short f2bf(float f) {
  unsigned u = __float_as_uint(f);
  unsigned r = u + 0x7fffu + ((u >> 16) & 1u);  // RNE
  return (unsigned short)(r >> 16);
}
__device__ __forceinline__ float bf2f(short s) {
  return __uint_as_float(((unsigned)(unsigned short)s) << 16);
}
__device__ __forceinline__ float fast_sigmoid(float z) {
  return 1.0f / (1.0f + __expf(-z));
}

__global__ __launch_bounds__(1024) void k_zero(float* __restrict__ p, int n4) {
  int i = blockIdx.x * blockDim.x + threadIdx.x;
  if (i < n4) ((float4*)p)[i] = make_float4(0.f, 0.f, 0.f, 0.f);
}

// One launch converts W1 (blk 0-7), W2 (blk 8-15), W4 (blk 16-31).
__global__ __launch_bounds__(256) void k_convert_all(
    const float* __restrict__ W1, const float* __restrict__ W2,
    const float* __restrict__ W4, short* __restrict__ W1t,
    short* __restrict__ W2t, short* __restrict__ W4t)
{
  int blk = blockIdx.x;
  const float* W; short* out; int kt;
  if (blk < 8)       { W = W1; out = W1t; kt = blk; }
  else if (blk < 16) { W = W2; out = W2t; kt = blk - 8; }
  else               { W = W4; out = W4t; kt = blk - 16; }
  int n = threadIdx.x;
  short tmp[32];
#pragma unroll
  for (int kk = 0; kk < 32; ++kk)
    tmp[kk] = (short)f2bf(W[(size_t)(kt * 32 + kk) * DIM + n]);
  size_t base = ((size_t)kt * 256 + n) * 32;
#pragma unroll
  for (int kk = 0; kk < 32; kk += 4)
    *(short4*)&out[base + kk] = *(short4*)&tmp[kk];
}

// stage 64x256 fp32 tile -> bf16 LDS (pitch LDSP), rows clamped to maxrow
__device__ __forceinline__ void stage_tile(const float* __restrict__ A, int row0,
                                           int maxrow, short* xs, int tid)
{
#pragma unroll
  for (int it = 0; it < 16; ++it) {
    int linear = it * 256 + tid;
    int r = linear >> 6;      // 64 float4 per row
    int c4 = linear & 63;
    int row = min(row0 + r, maxrow);
    float4 v = *(const float4*)&A[(size_t)row * DIM + c4 * 4];
    short4 o;
    o.x = (short)f2bf(v.x); o.y = (short)f2bf(v.y);
    o.z = (short)f2bf(v.z); o.w = (short)f2bf(v.w);
    *(short4*)&xs[r * LDSP + c4 * 4] = o;
  }
}

// k_prep: per 64-row tile: x -> bf16 LDS image -> dump to xbf16p,
// plus masked segment-sum into local_rep (batch sorted).
__global__ __launch_bounds__(256) void k_prep(
    const float* __restrict__ x, const int* __restrict__ batch,
    const float* __restrict__ mask, char* __restrict__ xbf16p,
    float* __restrict__ local_rep)
{
  __shared__ __align__(16) short xs[64 * LDSP];
  __shared__ int   seg_s[64];
  __shared__ float mask_s[64];
  const int tid = threadIdx.x;
  const int tile = blockIdx.x;
  const int row0 = tile * 64;

  stage_tile(x, row0, NROWS - 1, xs, tid);
  if (tid < 64) {
    int row = min(row0 + tid, NROWS - 1);
    seg_s[tid] = batch[row];
    mask_s[tid] = mask[row];
  }
  __syncthreads();

  // dump LDS image (33792 B = 2112 float4) to global
  float4* g4 = (float4*)(xbf16p + (size_t)tile * TILE_B);
  const float4* l4 = (const float4*)xs;
#pragma unroll
  for (int j = 0; j < 8; ++j)
    g4[j * 256 + tid] = l4[j * 256 + tid];
  if (tid < 64) g4[2048 + tid] = l4[2048 + tid];

  // masked segsum from LDS bf16
  const int col = tid;
  const int rmax = min(64, NROWS - row0);
  float acc = 0.f;
  int cur = seg_s[0];
  for (int r = 0; r < rmax; ++r) {
    int s = seg_s[r];
    float xv = bf2f(xs[r * LDSP + col]);
    if (s != cur) {
      atomicAdd(&local_rep[(size_t)cur * DIM + col], acc);
      acc = 0.f; cur = s;
    }
    acc = fmaf(xv, mask_s[r], acc);
  }
  atomicAdd(&local_rep[(size_t)cur * DIM + col], acc);
}

// K=256 MFMA pass: acc += xs(64x256 bf16) @ Wt(k-tiled bf16, cols 256)
__device__ __forceinline__ void mfma_pass(const short* xs, const short* __restrict__ Wt,
                                          floatx4 acc[4][4], int lane15, int quad, int n0)
{
  for (int kt = 0; kt < 8; ++kt) {
    short8 bfr[4], afr[4];
#pragma unroll
    for (int jn = 0; jn < 4; ++jn)
      bfr[jn] = *(const short8*)&Wt[(size_t)kt * 8192 + (n0 + jn * 16 + lane15) * 32 + quad * 8];
#pragma unroll
    for (int i = 0; i < 4; ++i)
      afr[i] = *(const short8*)&xs[(i * 16 + lane15) * LDSP + kt * 32 + quad * 8];
#pragma unroll
    for (int i = 0; i < 4; ++i)
#pragma unroll
      for (int jn = 0; jn < 4; ++jn)
        acc[i][jn] = __builtin_amdgcn_mfma_f32_16x16x32_bf16(afr[i], bfr[jn], acc[i][jn], 0, 0, 0);
  }
}

// H1 = bf16(local_rep @ W1 + b1)
__global__ __launch_bounds__(256) void k_h1_mfma(
    const float* __restrict__ A, const short* __restrict__ Wt,
    const float* __restrict__ bias, short* __restrict__ H1bf)
{
  __shared__ __align__(16) short xs[64 * LDSP];
  const int tid = threadIdx.x;
  const int row0 = blockIdx.x * 64;
  stage_tile(A, row0, BSEG - 1, xs, tid);
  __syncthreads();
  const int lane = tid & 63, wave = tid >> 6;
  const int lane15 = lane & 15, quad = lane >> 4;
  const int n0 = wave * 64;
  floatx4 acc[4][4];
#pragma unroll
  for (int i = 0; i < 4; ++i)
#pragma unroll
    for (int j = 0; j < 4; ++j) acc[i][j] = (floatx4)0.f;
  mfma_pass(xs, Wt, acc, lane15, quad, n0);
#pragma unroll
  for (int i = 0; i < 4; ++i)
#pragma unroll
    for (int jn = 0; jn < 4; ++jn) {
      int col = n0 + jn * 16 + lane15;
      float bv = bias[col];
#pragma unroll
      for (int r = 0; r < 4; ++r) {
        int row = row0 + i * 16 + quad * 4 + r;
        H1bf[(size_t)row * DIM + col] = (short)f2bf(acc[i][jn][r] + bv);
      }
    }
}

// Fused: z = x@W2 + b2 + H1[batch]; att = sigmoid(z)@w3; global_rep += segsum(x*att)
// x tile arrives pre-converted via async global_load_lds DMA (no VALU staging).
__global__ __launch_bounds__(256) void k_fused_main(
    const char* __restrict__ xbf16p, const int* __restrict__ batch,
    const short* __restrict__ W2t, const float* __restrict__ b2,
    const float* __restrict__ w3, const short* __restrict__ H1bf,
    float* __restrict__ global_rep)
{
  __shared__ __align__(16) short xs[64 * LDSP];
  __shared__ int   seg_s[64];
  __shared__ float att_s[64];
  const int tid = threadIdx.x;
  const int row0 = blockIdx.x * 64;
  const int lane = tid & 63, wave = tid >> 6;

  // async DMA the 33792-B tile image: 33 chunks of 1024 B, wave w takes
  // chunks {w, w+4, ...} (wave-uniform LDS base, lane*16 scatter by HW)
  {
    const char* gtile = xbf16p + (size_t)blockIdx.x * TILE_B;
    char* lbase = (char*)xs;
#pragma unroll
    for (int j = 0; j < 9; ++j) {
      int c = wave + 4 * j;
      if (c < 33)
        GLD16(gtile + (size_t)c * 1024 + lane * 16, lbase + c * 1024);
    }
  }
  if (tid < 64) {
    seg_s[tid] = batch[min(row0 + tid, NROWS - 1)];
    att_s[tid] = 0.f;
  }
  __syncthreads();   // drains vmcnt (global_load_lds) + lds writes

  const int lane15 = lane & 15, quad = lane >> 4;
  const int n0 = wave * 64;
  floatx4 acc[4][4];
#pragma unroll
  for (int i = 0; i < 4; ++i)
#pragma unroll
    for (int j = 0; j < 4; ++j) acc[i][j] = (floatx4)0.f;
  mfma_pass(xs, W2t, acc, lane15, quad, n0);

  // epilogue: z -> sigmoid -> dot w3 -> att per row
  float b2v[4], w3v[4];
#pragma unroll
  for (int jn = 0; jn < 4; ++jn) {
    int col = n0 + jn * 16 + lane15;
    b2v[jn] = b2[col];
    w3v[jn] = w3[col];
  }
  float part[4][4];
#pragma unroll
  for (int i = 0; i < 4; ++i)
#pragma unroll
    for (int r = 0; r < 4; ++r) {
      int rl = i * 16 + quad * 4 + r;
      int seg = seg_s[rl];
      float p = 0.f;
#pragma unroll
      for (int jn = 0; jn < 4; ++jn) {
        int col = n0 + jn * 16 + lane15;
        float h = bf2f(H1bf[(size_t)seg * DIM + col]);
        float z = acc[i][jn][r] + h + b2v[jn];
        p = fmaf(fast_sigmoid(z), w3v[jn], p);
      }
      part[i][r] = p;
    }
  // reduce over the 16 lanes (cols) of each quad
#pragma unroll
  for (int off = 1; off < 16; off <<= 1)
#pragma unroll
    for (int i = 0; i < 4; ++i)
#pragma unroll
      for (int r = 0; r < 4; ++r)
        part[i][r] += __shfl_xor(part[i][r], off, 64);
  if (lane15 == 0) {
#pragma unroll
    for (int i = 0; i < 4; ++i)
#pragma unroll
      for (int r = 0; r < 4; ++r)
        atomicAdd(&att_s[i * 16 + quad * 4 + r], part[i][r]);
  }
  __syncthreads();

  // phase 2: weighted segsum of x*att from LDS (bf16 x)
  const int col = tid;
  const int rmax = min(64, NROWS - row0);
  float acc2 = 0.f;
  int cur = seg_s[0];
  for (int r = 0; r < rmax; ++r) {
    int s = seg_s[r];
    float xv = bf2f(xs[r * LDSP + col]);
    float av = att_s[r];
    if (s != cur) {
      atomicAdd(&global_rep[(size_t)cur * DIM + col], acc2);
      acc2 = 0.f; cur = s;
    }
    acc2 = fmaf(xv, av, acc2);
  }
  atomicAdd(&global_rep[(size_t)cur * DIM + col], acc2);
}

// out = local_rep @ W4[0:256] + global_rep @ W4[256:512] + b4
__global__ __launch_bounds__(256) void k_out_mfma(
    const float* __restrict__ local_rep, const float* __restrict__ global_rep,
    const short* __restrict__ W4t, const float* __restrict__ b4,
    float* __restrict__ out)
{
  __shared__ __align__(16) short xs[64 * LDSP];
  const int tid = threadIdx.x;
  const int row0 = blockIdx.x * 64;
  const int lane = tid & 63, wave = tid >> 6;
  const int lane15 = lane & 15, quad = lane >> 4;
  const int n0 = wave * 64;
  floatx4 acc[4][4];
#pragma unroll
  for (int i = 0; i < 4; ++i)
#pragma unroll
    for (int j = 0; j < 4; ++j) acc[i][j] = (floatx4)0.f;

  stage_tile(local_rep, row0, BSEG - 1, xs, tid);
  __syncthreads();
  mfma_pass(xs, W4t, acc, lane15, quad, n0);
  __syncthreads();
  stage_tile(global_rep, row0, BSEG - 1, xs, tid);
  __syncthreads();
  mfma_pass(xs, W4t + (size_t)8 * 8192, acc, lane15, quad, n0);

#pragma unroll
  for (int i = 0; i < 4; ++i)
#pragma unroll
    for (int jn = 0; jn < 4; ++jn) {
      int col = n0 + jn * 16 + lane15;
      float bv = b4[col];
#pragma unroll
      for (int r = 0; r < 4; ++r) {
        int row = row0 + i * 16 + quad * 4 + r;
        out[(size_t)row * DIM + col] = acc[i][jn][r] + bv;
      }
    }
}

extern "C" void kernel_launch(void* const* d_in, const int* in_sizes, int n_in,
                              void* d_out, int out_size, void* d_ws, size_t ws_size,
                              hipStream_t stream) {
  (void)in_sizes; (void)n_in; (void)out_size; (void)ws_size;
  const float* x    = (const float*)d_in[0];
  const int*   batch= (const int*)d_in[1];
  const float* mask = (const float*)d_in[2];
  const float* W1 = (const float*)d_in[4];
  const float* b1 = (const float*)d_in[5];
  const float* W2 = (const float*)d_in[6];
  const float* b2 = (const float*)d_in[7];
  const float* w3 = (const float*)d_in[8];
  const float* W4 = (const float*)d_in[9];
  const float* b4 = (const float*)d_in[10];
  float* out = (float*)d_out;

  char* base = (char*)d_ws;
  float* local_rep  = (float*)(base);
  float* global_rep = (float*)(base + (size_t)16 * 1024 * 1024);
  short* H1bf       = (short*)(base + (size_t)32 * 1024 * 1024);
  short* W1t        = (short*)(base + (size_t)40 * 1024 * 1024);
  short* W2t        = (short*)(base + (size_t)40 * 1024 * 1024 + 128 * 1024);
  short* W4t        = (short*)(base + (size_t)40 * 1024 * 1024 + 256 * 1024);
  char*  xbf16p     = base + (size_t)48 * 1024 * 1024;

  // zero local_rep + global_rep (33.5 MB)
  int n4 = 2 * BSEG * DIM / 4;
  hipLaunchKernelGGL(k_zero, dim3(n4 / 1024), dim3(1024), 0, stream, local_rep, n4);

  // all weight conversions in one launch
  hipLaunchKernelGGL(k_convert_all, dim3(32), dim3(256), 0, stream,
                     W1, W2, W4, W1t, W2t, W4t);

  // x -> bf16 tile images + masked segsum
  hipLaunchKernelGGL(k_prep, dim3(NTILE), dim3(256), 0, stream,
                     x, batch, mask, xbf16p, local_rep);

  hipLaunchKernelGGL(k_h1_mfma, dim3(BSEG / 64), dim3(256), 0, stream,
                     local_rep, W1t, b1, H1bf);

  hipLaunchKernelGGL(k_fused_main, dim3(NTILE), dim3(256), 0, stream,
                     xbf16p, batch, W2t, b2, w3, H1bf, global_rep);

  hipLaunchKernelGGL(k_out_mfma, dim3(BSEG / 64), dim3(256), 0, stream,
                     local_rep, global_rep, W4t, b4, out);
}